// Round 4
// baseline (559.094 us; speedup 1.0000x reference)
//
#include <hip/hip_runtime.h>
#include <cstdint>

#define NUM_CLASSES 81
#define BB 32
#define PP 32768
#define CA 32                               // anchors per chunk
#define TPB 256
#define CHUNK_FLOATS (CA * NUM_CLASSES)     // 2592
#define CHUNK_F4 (CHUNK_FLOATS / 4)         // 648
#define NCHUNK (BB * PP / CA)               // 32768
#define GRID_MAIN 1792                      // 7 blocks/CU * 256 CU
#define NP_STRIDE 32                        // num_pos padded: 1 counter per 128 B
#define NBIN 4096
#define LCAP 16384

__device__ __forceinline__ unsigned f2key(float f) {
    unsigned u = __float_as_uint(f);
    return u ^ (unsigned)(((int)u >> 31) | (int)0x80000000u);
}
__device__ __forceinline__ float key2f(unsigned k) {
    unsigned u = (k & 0x80000000u) ? (k ^ 0x80000000u) : ~k;
    return __uint_as_float(u);
}

#define GLDS16(gp, lp) __builtin_amdgcn_global_load_lds( \
    (const __attribute__((address_space(1))) void*)(gp), \
    (__attribute__((address_space(3))) void*)(lp), 16, 0, 0)

// ws layout: [4 MB loss_c][acc: 4 floats][pad to +256][num_pos: 32*NP_STRIDE ints]

__global__ void mbl_zero_kernel(unsigned* __restrict__ p, int n) {
    for (int i = threadIdx.x; i < n; i += 1024) p[i] = 0u;
}

__global__ __launch_bounds__(TPB, 7) void mbl_main_kernel(
    const float* __restrict__ loc_t, const float* __restrict__ loc_data,
    const int* __restrict__ conf_t, const float* __restrict__ conf,
    float* __restrict__ loss_c, float* __restrict__ acc, int* __restrict__ num_pos)
{
    __shared__ __align__(16) float tile[2][CHUNK_FLOATS];   // 2 x 10368 B
    __shared__ float wred[2][TPB / 64];

    const int t = threadIdx.x;
    const int lane = t & 63;
    const int g = t >> 3;      // anchor in chunk 0..31
    const int r = t & 7;       // lane-in-group 0..7

    float sum_ll = 0.f, sum_pce = 0.f;

    int c = blockIdx.x;
    {   // prologue: async-stage first chunk into buffer 0
        const float4* s4 = (const float4*)(conf + (size_t)c * CHUNK_FLOATS);
        float4* d4 = (float4*)tile[0];
        GLDS16(s4 + t, d4 + t);
        GLDS16(s4 + t + 256, d4 + t + 256);
        if (t < CHUNK_F4 - 512) GLDS16(s4 + t + 512, d4 + t + 512);
    }
    __syncthreads();

    int parity = 0;
    const int stride = gridDim.x;
    for (; c < NCHUNK; c += stride) {
        const int nc = c + stride;
        if (nc < NCHUNK) {   // async-stage next chunk into other buffer
            const float4* s4 = (const float4*)(conf + (size_t)nc * CHUNK_FLOATS);
            float4* d4 = (float4*)tile[parity ^ 1];
            GLDS16(s4 + t, d4 + t);
            GLDS16(s4 + t + 256, d4 + t + 256);
            if (t < CHUNK_F4 - 512) GLDS16(s4 + t + 512, d4 + t + 512);
        }
        // ---- compute chunk c from tile[parity] ----
        const float* cp = tile[parity] + g * NUM_CLASSES + r * 10;
        float s = 0.f;
        #pragma unroll
        for (int j = 0; j < 10; ++j) s += __expf(cp[j]);
        if (r == 0) s += __expf(tile[parity][g * NUM_CLASSES + 80]);
        s += __shfl_xor(s, 1);
        s += __shfl_xor(s, 2);
        s += __shfl_xor(s, 4);   // all 8 lanes of the group now hold the full sum

        bool posl = false;
        if (r == 0) {
            const int idx = c * CA + g;
            const int label = conf_t[idx];
            posl = label > 0;
            const bool regard = label == -1;
            const int lab = label < 0 ? 0 : label;
            const float gv = tile[parity][g * NUM_CLASSES + lab];
            const float ce = __logf(s) - gv;
            loss_c[idx] = (posl || regard) ? 0.f : ce;
            if (posl) {
                float4 a4 = ((const float4*)loc_data)[idx];
                float4 b4 = ((const float4*)loc_t)[idx];
                float d0 = fabsf(a4.x - b4.x), d1 = fabsf(a4.y - b4.y);
                float d2 = fabsf(a4.z - b4.z), d3 = fabsf(a4.w - b4.w);
                sum_ll += (d0 < 1.f) ? 0.5f * d0 * d0 : d0 - 0.5f;
                sum_ll += (d1 < 1.f) ? 0.5f * d1 * d1 : d1 - 0.5f;
                sum_ll += (d2 < 1.f) ? 0.5f * d2 * d2 : d2 - 0.5f;
                sum_ll += (d3 < 1.f) ? 0.5f * d3 * d3 : d3 - 0.5f;
                sum_pce += ce;
            }
        }
        unsigned long long bal = __ballot(posl);
        if (lane == 0 && bal)
            atomicAdd(&num_pos[(c >> 10) * NP_STRIDE], (int)__popcll(bal));
        __syncthreads();   // next buffer staged (vmcnt drained) + everyone done with cur
        parity ^= 1;
    }
    #pragma unroll
    for (int off = 32; off > 0; off >>= 1) {
        sum_ll += __shfl_down(sum_ll, off);
        sum_pce += __shfl_down(sum_pce, off);
    }
    const int w = t >> 6;
    if (lane == 0) { wred[0][w] = sum_ll; wred[1][w] = sum_pce; }
    __syncthreads();
    if (t == 0) {
        float s0 = 0.f, s1 = 0.f;
        #pragma unroll
        for (int i = 0; i < TPB / 64; ++i) { s0 += wred[0][i]; s1 += wred[1][i]; }
        atomicAdd(&acc[0], s0);
        atomicAdd(&acc[1], s1);
    }
}

// One block per batch row. 4096-bin (count,sum) histogram on key>>19, suffix
// scan -> threshold bin; compact bin elements; 2-pass in-LDS radix on the low
// 19 bits -> exact k-th-largest threshold + tie count; sum of top-k -> acc[2].
__global__ __launch_bounds__(1024) void mbl_select_kernel(
    const float* __restrict__ loss_c, const int* __restrict__ num_pos,
    float* __restrict__ acc)
{
    __shared__ unsigned cnt[NBIN];
    __shared__ float fsum[NBIN];
    __shared__ float list[LCAP];
    __shared__ unsigned sh_nlist, sh_B, sh_r, sh_D1, sh_r2, sh_D0, sh_rem;
    __shared__ float sh_above;
    __shared__ float wr[16];

    const int b = blockIdx.x;
    const int t = threadIdx.x;
    int k = 3 * num_pos[b * NP_STRIDE];
    if (k > PP - 1) k = PP - 1;
    if (k <= 0) return;  // uniform across block

    #pragma unroll
    for (int i = 0; i < NBIN / 1024; ++i) { cnt[t + i * 1024] = 0u; fsum[t + i * 1024] = 0.f; }
    if (t == 0) sh_nlist = 0u;
    __syncthreads();

    const float4* r4 = (const float4*)(loss_c + (size_t)b * PP);
    float4 vv[8];
    #pragma unroll
    for (int i = 0; i < 8; ++i) vv[i] = r4[t + i * 1024];
    #pragma unroll
    for (int i = 0; i < 8; ++i) {
        float vals[4] = {vv[i].x, vv[i].y, vv[i].z, vv[i].w};
        #pragma unroll
        for (int j = 0; j < 4; ++j) {
            float v = vals[j];
            unsigned bin = (f2key(v) >> 19) - 4096u;   // loss_c >= 0 -> key >= 0x80000000
            bin = bin > 4095u ? 4095u : bin;
            atomicAdd(&cnt[bin], 1u);
            atomicAdd(&fsum[bin], v);
        }
    }
    __syncthreads();

    // suffix scans (count + sum), Hillis-Steele over 4096 bins
    for (int step = 1; step < NBIN; step <<= 1) {
        unsigned c0[4]; float s0[4];
        #pragma unroll
        for (int i = 0; i < 4; ++i) {
            int j = t + i * 1024, jj = j + step;
            c0[i] = cnt[j] + (jj < NBIN ? cnt[jj] : 0u);
            s0[i] = fsum[j] + (jj < NBIN ? fsum[jj] : 0.f);
        }
        __syncthreads();
        #pragma unroll
        for (int i = 0; i < 4; ++i) { int j = t + i * 1024; cnt[j] = c0[i]; fsum[j] = s0[i]; }
        __syncthreads();
    }
    const unsigned kk = (unsigned)k;
    #pragma unroll
    for (int i = 0; i < 4; ++i) {
        int j = t + i * 1024;
        unsigned here = cnt[j], above = (j < NBIN - 1) ? cnt[j + 1] : 0u;
        if (here >= kk && above < kk) {
            sh_B = (unsigned)j; sh_r = kk - above;
            sh_above = (j < NBIN - 1) ? fsum[j + 1] : 0.f;
        }
    }
    __syncthreads();
    const unsigned B = sh_B;
    const unsigned r = sh_r;
    const float sum_above = sh_above;

    // compact elements of bin B
    #pragma unroll
    for (int i = 0; i < 8; ++i) {
        float vals[4] = {vv[i].x, vv[i].y, vv[i].z, vv[i].w};
        #pragma unroll
        for (int j = 0; j < 4; ++j) {
            float v = vals[j];
            unsigned bin = (f2key(v) >> 19) - 4096u;
            bin = bin > 4095u ? 4095u : bin;
            if (bin == B) { unsigned p = atomicAdd(&sh_nlist, 1u); if (p < LCAP) list[p] = v; }
        }
    }
    __syncthreads();
    unsigned n = sh_nlist; if (n > LCAP) n = LCAP;

    // radix pass 1: bits 18:9 (1024 bins)
    cnt[t] = 0u;
    __syncthreads();
    for (unsigned e = t; e < n; e += 1024)
        atomicAdd(&cnt[(f2key(list[e]) >> 9) & 1023u], 1u);
    __syncthreads();
    for (int step = 1; step < 1024; step <<= 1) {
        unsigned v = cnt[t] + (t + step < 1024 ? cnt[t + step] : 0u);
        __syncthreads(); cnt[t] = v; __syncthreads();
    }
    {
        unsigned here = cnt[t], above = (t < 1023) ? cnt[t + 1] : 0u;
        if (here >= r && above < r) { sh_D1 = (unsigned)t; sh_r2 = r - above; }
    }
    __syncthreads();
    const unsigned D1 = sh_D1;
    const unsigned r2 = sh_r2;

    // radix pass 2: bits 8:0 (512 bins)
    if (t < 512) cnt[t] = 0u;
    __syncthreads();
    for (unsigned e = t; e < n; e += 1024) {
        unsigned key = f2key(list[e]);
        if (((key >> 9) & 1023u) == D1) atomicAdd(&cnt[key & 511u], 1u);
    }
    __syncthreads();
    for (int step = 1; step < 512; step <<= 1) {
        unsigned v = 0u;
        if (t < 512) v = cnt[t] + (t + step < 512 ? cnt[t + step] : 0u);
        __syncthreads();
        if (t < 512) cnt[t] = v;
        __syncthreads();
    }
    if (t < 512) {
        unsigned here = cnt[t], above = (t < 511) ? cnt[t + 1] : 0u;
        if (here >= r2 && above < r2) { sh_D0 = (unsigned)t; sh_rem = r2 - above; }
    }
    __syncthreads();
    const unsigned T = ((B + 4096u) << 19) | (D1 << 9) | sh_D0;
    const unsigned rem = sh_rem;

    float part = 0.f;
    for (unsigned e = t; e < n; e += 1024) {
        float v = list[e];
        if (f2key(v) > T) part += v;
    }
    #pragma unroll
    for (int off = 32; off > 0; off >>= 1) part += __shfl_down(part, off);
    if ((t & 63) == 0) wr[t >> 6] = part;
    __syncthreads();
    if (t == 0) {
        float tot = sum_above + (float)rem * key2f(T);
        #pragma unroll
        for (int i = 0; i < 16; ++i) tot += wr[i];
        atomicAdd(&acc[2], tot);
    }
}

__global__ void mbl_final_kernel(const float* __restrict__ acc,
                                 const int* __restrict__ num_pos,
                                 float* __restrict__ out)
{
    if (threadIdx.x == 0 && blockIdx.x == 0) {
        int n = 0;
        for (int i = 0; i < BB; ++i) n += num_pos[i * NP_STRIDE];
        const float N = (float)n;
        out[0] = acc[0] / N;
        out[1] = (acc[1] + acc[2]) / N;
    }
}

extern "C" void kernel_launch(void* const* d_in, const int* in_sizes, int n_in,
                              void* d_out, int out_size, void* d_ws, size_t ws_size,
                              hipStream_t stream) {
    const float* loc_t    = (const float*)d_in[0];
    const float* loc_data = (const float*)d_in[1];
    const int*   conf_t   = (const int*)d_in[2];
    const float* conf     = (const float*)d_in[3];
    float* out = (float*)d_out;

    char* ws = (char*)d_ws;
    const size_t off0 = (size_t)BB * PP * sizeof(float);   // 4 MB loss_c
    float* loss_c  = (float*)ws;
    float* acc     = (float*)(ws + off0);
    int*   num_pos = (int*)(ws + off0 + 256);

    // zero acc + num_pos region: (256 + 32*NP_STRIDE*4) bytes = 1112 words
    mbl_zero_kernel<<<1, 1024, 0, stream>>>((unsigned*)(ws + off0), 1112);

    mbl_main_kernel<<<GRID_MAIN, TPB, 0, stream>>>(
        loc_t, loc_data, conf_t, conf, loss_c, acc, num_pos);

    mbl_select_kernel<<<BB, 1024, 0, stream>>>(loss_c, num_pos, acc);
    mbl_final_kernel<<<1, 64, 0, stream>>>(acc, num_pos, out);
}